// Round 10
// baseline (1922.113 us; speedup 1.0000x reference)
//
#include <hip/hip_runtime.h>
#include <hip/hip_bf16.h>
#include <hip/hip_cooperative_groups.h>
#include <math.h>

namespace cg = cooperative_groups;

#define N_NODES 100000
#define N_EDGES 3200000
#define FEAT 512
#define HID 256
#define CLS 64
#define K_ITER 10
#define NBUCK 196            // ceil(100000 / 512) node buckets of width 512
#define BSH 9                // bucket = r >> 9
#define CH 16384             // edges per chunk
#define NCHUNK 196           // ceil(N_EDGES / CH)

typedef _Float16 half8 __attribute__((ext_vector_type(8)));
typedef float f32x4 __attribute__((ext_vector_type(4)));

// ---------- edge index access (int32 or int64, detected at runtime) ----------
__device__ __forceinline__ int edge_at(const void* e, int is64, long long idx) {
    return is64 ? (int)((const long long*)e)[idx] : ((const int*)e)[idx];
}

__global__ void k_detect(const unsigned* __restrict__ e, int* __restrict__ flag,
                         int* __restrict__ bcntR, int* __restrict__ bcntC) {
    __shared__ unsigned s[256];
    unsigned v = 0;
    for (int i = threadIdx.x; i < 4096; i += 256) v |= e[2 * i + 1];
    s[threadIdx.x] = v;
    __syncthreads();
    for (int off = 128; off; off >>= 1) {
        if (threadIdx.x < off) s[threadIdx.x] |= s[threadIdx.x + off];
        __syncthreads();
    }
    if (threadIdx.x == 0) flag[0] = (s[0] == 0) ? 1 : 0;
    if (threadIdx.x < NBUCK) { bcntR[threadIdx.x] = 0; bcntC[threadIdx.x] = 0; }
}

// ---------- phase 1: per-chunk bucket histograms (r and c) ----------
__global__ __launch_bounds__(256) void k_bhist(const void* __restrict__ e,
                                               const int* __restrict__ flag,
                                               int* __restrict__ bcntR,
                                               int* __restrict__ bcntC,
                                               int* __restrict__ histR,
                                               int* __restrict__ histC) {
    __shared__ int lhR[NBUCK], lhC[NBUCK];
    for (int i = threadIdx.x; i < NBUCK; i += 256) { lhR[i] = 0; lhC[i] = 0; }
    __syncthreads();
    int is64 = flag[0];
    const int ch = blockIdx.x;
    long long base = (long long)ch * CH;
    for (int j = threadIdx.x; j < CH; j += 256) {
        long long i = base + j;
        if (i < N_EDGES) {
            int r = edge_at(e, is64, i);
            int c = edge_at(e, is64, (long long)N_EDGES + i);
            atomicAdd(&lhR[r >> BSH], 1);
            atomicAdd(&lhC[c >> BSH], 1);
        }
    }
    __syncthreads();
    for (int i = threadIdx.x; i < NBUCK; i += 256) {
        histR[ch * NBUCK + i] = lhR[i];
        histC[ch * NBUCK + i] = lhC[i];
        if (lhR[i]) atomicAdd(&bcntR[i], lhR[i]);
        if (lhC[i]) atomicAdd(&bcntC[i], lhC[i]);
    }
}

// ---------- phase 2a: bucket base scan (196 entries; trivial serial) ----------
__global__ void k_bscan(const int* __restrict__ bcntR, const int* __restrict__ bcntC,
                        int* __restrict__ bbaseR, int* __restrict__ bbaseC,
                        int* __restrict__ cbase, int* __restrict__ offs) {
    if (threadIdx.x == 0) {
        int accE = 0, accC = 0, accCv = 0;
        for (int b = 0; b < NBUCK; b++) {
            bbaseR[b] = accE;
            bbaseC[b] = accCv;
            cbase[b] = accC;
            int nb0 = b << BSH;
            int nn = (N_NODES - nb0 < 512) ? (N_NODES - nb0) : 512;
            accE += bcntR[b];
            accCv += bcntC[b];
            accC += bcntR[b] + nn;
        }
        bbaseR[NBUCK] = accE;
        bbaseC[NBUCK] = accCv;
        cbase[NBUCK] = accC;
        offs[N_NODES] = accC;
    }
}

// ---------- phase 2b: per-(chunk,bucket) bases (scan over chunks) ----------
__global__ __launch_bounds__(256) void k_bscan2(const int* __restrict__ histR,
                                                const int* __restrict__ bbaseR,
                                                int* __restrict__ baseR,
                                                const int* __restrict__ histC,
                                                const int* __restrict__ bbaseC,
                                                int* __restrict__ baseC) {
    __shared__ int s[256];
    const int t = threadIdx.x;
    const int* hist;
    const int* bb;
    int* bout;
    int b;
    if (blockIdx.x < NBUCK) { hist = histR; bb = bbaseR; bout = baseR; b = blockIdx.x; }
    else { hist = histC; bb = bbaseC; bout = baseC; b = blockIdx.x - NBUCK; }
    int v = (t < NCHUNK) ? hist[t * NBUCK + b] : 0;
    s[t] = v;
    __syncthreads();
    for (int off = 1; off < 256; off <<= 1) {
        int a = (t >= off) ? s[t - off] : 0;
        __syncthreads();
        s[t] += a;
        __syncthreads();
    }
    if (t < NCHUNK) bout[t * NBUCK + b] = bb[b] + s[t] - v;
}

// ---------- phase 3: place edges into bucket-contiguous runs (no global atomics) ----------
// pairs entry (r-binned): (c << 9) | (r & 511)   [26 bits used]
__global__ __launch_bounds__(256) void k_binA(const void* __restrict__ e,
                                              const int* __restrict__ flag,
                                              const int* __restrict__ baseR,
                                              const int* __restrict__ baseC,
                                              unsigned* __restrict__ pairs,
                                              int* __restrict__ cvals) {
    __shared__ int lbR[NBUCK], lcR[NBUCK], lbC[NBUCK], lcC[NBUCK];
    const int ch = blockIdx.x;
    for (int i = threadIdx.x; i < NBUCK; i += 256) {
        lbR[i] = baseR[ch * NBUCK + i];
        lcR[i] = 0;
        lbC[i] = baseC[ch * NBUCK + i];
        lcC[i] = 0;
    }
    __syncthreads();
    int is64 = flag[0];
    long long base = (long long)ch * CH;
    for (int j = threadIdx.x; j < CH; j += 256) {
        long long i = base + j;
        if (i < N_EDGES) {
            int r = edge_at(e, is64, i);
            int c = edge_at(e, is64, (long long)N_EDGES + i);
            int b = r >> BSH;
            int pos = atomicAdd(&lcR[b], 1);
            pairs[(long long)lbR[b] + pos] = ((unsigned)c << 9) | (unsigned)(r & 511);
            int bc = c >> BSH;
            int posc = atomicAdd(&lcC[bc], 1);
            cvals[(long long)lbC[bc] + posc] = c;
        }
    }
}

// ---------- merged per-bucket pass: deg/dinv (blocks 0..195) + CSR build (196..391) ----------
__global__ __launch_bounds__(1024) void k_bins(const int* __restrict__ cvals,
                                               const int* __restrict__ bbaseC,
                                               float* __restrict__ dinv,
                                               const unsigned* __restrict__ pairs,
                                               const int* __restrict__ bbaseR,
                                               const int* __restrict__ cbase,
                                               int* __restrict__ offs,
                                               int* __restrict__ ccol) {
    __shared__ int cnt[512], cur[512], s[512];
    const int t = threadIdx.x;
    if (blockIdx.x < NBUCK) {
        // degree count over c occurrences
        const int b = blockIdx.x;
        const int nb0 = b << BSH;
        const int nn = (N_NODES - nb0 < 512) ? (N_NODES - nb0) : 512;
        if (t < 512) cnt[t] = 1;  // self loop
        __syncthreads();
        const int e0 = bbaseC[b], e1 = bbaseC[b + 1];
        for (int i = e0 + t; i < e1; i += 1024) {
            atomicAdd(&cnt[cvals[i] - nb0], 1);
        }
        __syncthreads();
        if (t < nn) dinv[nb0 + t] = rsqrtf((float)cnt[t]);
        return;
    }
    // CSR build
    const int b = blockIdx.x - NBUCK;
    const int nb0 = b << BSH;
    const int nn = (N_NODES - nb0 < 512) ? (N_NODES - nb0) : 512;
    if (t < 512) cnt[t] = (t < nn) ? 1 : 0;  // self loop
    __syncthreads();
    const int e0 = bbaseR[b], e1 = bbaseR[b + 1];
    for (int i = e0 + t; i < e1; i += 1024) {
        atomicAdd(&cnt[pairs[i] & 511u], 1);
    }
    __syncthreads();
    // exclusive scan of cnt[0..511]
    int v = (t < 512) ? cnt[t] : 0;
    if (t < 512) s[t] = v;
    __syncthreads();
    for (int off = 1; off < 512; off <<= 1) {
        int a = 0;
        if (t < 512 && t >= off) a = s[t - off];
        __syncthreads();
        if (t < 512) s[t] += a;
        __syncthreads();
    }
    const int cb = cbase[b];
    if (t < 512) {
        int excl = s[t] - v;
        cur[t] = excl;
        if (t < nn) {
            offs[nb0 + t] = cb + excl;
            ccol[cb + excl] = nb0 + t;  // self loop entry
            cur[t] = excl + 1;
        }
    }
    __syncthreads();
    for (int i = e0 + t; i < e1; i += 1024) {
        unsigned p = pairs[i];
        int r = (int)(p & 511u);
        int c = (int)(p >> 9);
        int pos = atomicAdd(&cur[r], 1);
        ccol[cb + pos] = c;
    }
}

// ---------- weight transpose + fp16 convert ----------
__global__ void k_cvtW(const float* __restrict__ W1, const float* __restrict__ W2,
                       _Float16* __restrict__ W1T, _Float16* __restrict__ W2T) {
    int i = blockIdx.x * 256 + threadIdx.x;
    if (i < 256 * 512) {
        int n = i >> 9, k = i & 511;
        W1T[i] = (_Float16)W1[k * 256 + n];
    }
    if (i < 64 * 256) {
        int n = i >> 8, k = i & 255;
        W2T[i] = (_Float16)W2[k * 64 + n];
    }
}

// swizzle helper: physical granule for (row, logical granule)
__device__ __forceinline__ int swz(int row, int g) {
    return g ^ (row & 3) ^ ((row >> 2) & 3);
}

// ---------- GEMM1: h1[M][256](fp16) = relu(x[M][512](fp32) @ W1 + b1) ----------
__global__ __launch_bounds__(512) void k_gemm1(const float* __restrict__ A,
                                               const _Float16* __restrict__ BT,
                                               const float* __restrict__ bias,
                                               _Float16* __restrict__ C, int M) {
    __shared__ __align__(16) char lds[8192 + 16384];
    const int t = threadIdx.x;
    const int wid = t >> 6, lane = t & 63;
    const int wr = wid >> 2, wc = wid & 3;
    const int srow = t >> 2, sg = t & 3;
    const int fr = lane & 15, fg = lane >> 4;
    const long long by = blockIdx.x;

    f32x4 acc[4][4] = {};
    const long long arow = by * 128 + srow;
    const bool avalid = (arow < M);
    const float* ap0 = A + arow * FEAT + sg * 8;

    for (int kt = 0; kt < FEAT; kt += 32) {
        float4 a0 = make_float4(0.f, 0.f, 0.f, 0.f), a1 = a0;
        if (avalid) {
            const float* ap = ap0 + kt;
            a0 = *(const float4*)ap;
            a1 = *(const float4*)(ap + 4);
        }
        half8 ah;
        ah[0] = (_Float16)a0.x; ah[1] = (_Float16)a0.y;
        ah[2] = (_Float16)a0.z; ah[3] = (_Float16)a0.w;
        ah[4] = (_Float16)a1.x; ah[5] = (_Float16)a1.y;
        ah[6] = (_Float16)a1.z; ah[7] = (_Float16)a1.w;
        *(half8*)(lds + srow * 64 + swz(srow, sg) * 16) = ah;
#pragma unroll
        for (int rep = 0; rep < 2; rep++) {
            int brow = rep * 128 + srow;
            half8 bh = *(const half8*)(BT + brow * FEAT + kt + sg * 8);
            *(half8*)(lds + 8192 + brow * 64 + swz(brow, sg) * 16) = bh;
        }
        __syncthreads();

        half8 af[4], bf[4];
#pragma unroll
        for (int mi = 0; mi < 4; mi++) {
            int r = wr * 64 + mi * 16 + fr;
            af[mi] = *(const half8*)(lds + r * 64 + swz(r, fg) * 16);
        }
#pragma unroll
        for (int nj = 0; nj < 4; nj++) {
            int r = wc * 64 + nj * 16 + fr;
            bf[nj] = *(const half8*)(lds + 8192 + r * 64 + swz(r, fg) * 16);
        }
#pragma unroll
        for (int mi = 0; mi < 4; mi++)
#pragma unroll
            for (int nj = 0; nj < 4; nj++)
                acc[mi][nj] = __builtin_amdgcn_mfma_f32_16x16x32_f16(af[mi], bf[nj], acc[mi][nj], 0, 0, 0);
        __syncthreads();
    }

#pragma unroll
    for (int mi = 0; mi < 4; mi++) {
#pragma unroll
        for (int nj = 0; nj < 4; nj++) {
            int col = wc * 64 + nj * 16 + fr;
            float bv = bias[col];
#pragma unroll
            for (int r = 0; r < 4; r++) {
                long long row = by * 128 + wr * 64 + mi * 16 + fg * 4 + r;
                if (row < M) {
                    float v = fmaxf(acc[mi][nj][r] + bv, 0.f);
                    C[row * HID + col] = (_Float16)v;
                }
            }
        }
    }
}

// ---------- GEMM2: h[M][64](fp16), s0[M][64](fp16 = dinv*h) ----------
__global__ __launch_bounds__(512) void k_gemm2(const _Float16* __restrict__ A,
                                               const _Float16* __restrict__ BT,
                                               const float* __restrict__ bias,
                                               const float* __restrict__ dinv,
                                               _Float16* __restrict__ Hout,
                                               _Float16* __restrict__ S0, int M) {
    __shared__ __align__(16) char lds[16384 + 4096];
    const int t = threadIdx.x;
    const int wid = t >> 6, lane = t & 63;
    const int wr = wid >> 1, wc = wid & 1;
    const int srow = t >> 2, sg = t & 3;
    const int fr = lane & 15, fg = lane >> 4;
    const long long bm = blockIdx.x;

    f32x4 acc[4][2] = {};

    for (int kt = 0; kt < HID; kt += 32) {
#pragma unroll
        for (int rep = 0; rep < 2; rep++) {
            int ar = rep * 128 + srow;
            long long grow = bm * 256 + ar;
            if (grow >= M) grow = M - 1;
            half8 ah = *(const half8*)(A + grow * HID + kt + sg * 8);
            *(half8*)(lds + ar * 64 + swz(ar, sg) * 16) = ah;
        }
        if (t < 256) {
            int br = t >> 2;
            half8 bh = *(const half8*)(BT + br * HID + kt + sg * 8);
            *(half8*)(lds + 16384 + br * 64 + swz(br, sg) * 16) = bh;
        }
        __syncthreads();

        half8 af[4], bf[2];
#pragma unroll
        for (int mi = 0; mi < 4; mi++) {
            int r = wr * 64 + mi * 16 + fr;
            af[mi] = *(const half8*)(lds + r * 64 + swz(r, fg) * 16);
        }
#pragma unroll
        for (int nj = 0; nj < 2; nj++) {
            int r = wc * 32 + nj * 16 + fr;
            bf[nj] = *(const half8*)(lds + 16384 + r * 64 + swz(r, fg) * 16);
        }
#pragma unroll
        for (int mi = 0; mi < 4; mi++)
#pragma unroll
            for (int nj = 0; nj < 2; nj++)
                acc[mi][nj] = __builtin_amdgcn_mfma_f32_16x16x32_f16(af[mi], bf[nj], acc[mi][nj], 0, 0, 0);
        __syncthreads();
    }

#pragma unroll
    for (int mi = 0; mi < 4; mi++) {
#pragma unroll
        for (int nj = 0; nj < 2; nj++) {
            int col = wc * 32 + nj * 16 + fr;
            float bv = bias[col];
#pragma unroll
            for (int r = 0; r < 4; r++) {
                long long row = bm * 256 + wr * 64 + mi * 16 + fg * 4 + r;
                if (row < M) {
                    float o = acc[mi][nj][r] + bv;
                    Hout[row * CLS + col] = (_Float16)o;
                    S0[row * CLS + col] = (_Float16)(dinv[row] * o);
                }
            }
        }
    }
}

// ---------- fused propagation: all K iterations in one cooperative kernel ----------
// Persistent waves; wave w handles nodes w, w+nwaves, ... every iteration (keeps
// its offs/ccol slice hot in its XCD's L2 across all 10 hops). grid.sync()
// between hops provides device-scope visibility. No early returns (sync safety).
__global__ __launch_bounds__(256) void k_prop_all(const int* __restrict__ ccol,
                                                  const int* __restrict__ offs,
                                                  const float* __restrict__ dinv,
                                                  const _Float16* __restrict__ s0,
                                                  const _Float16* __restrict__ h,
                                                  _Float16* __restrict__ bufA,
                                                  _Float16* __restrict__ bufB,
                                                  float* __restrict__ out,
                                                  int nwaves) {
    cg::grid_group gg = cg::this_grid();
    const int gw = (blockIdx.x << 2) + (threadIdx.x >> 6);
    const int lane = threadIdx.x & 63;
    const int g = lane >> 3;
    const int sl = lane & 7;

    for (int it = 0; it < K_ITER; it++) {
        const _Float16* src = (it == 0) ? s0 : ((it & 1) ? bufA : bufB);
        _Float16* dst = (it & 1) ? bufB : bufA;
        const int last = (it == K_ITER - 1);

        for (int wid = gw; wid < N_NODES; wid += nwaves) {
            const int e0 = offs[wid], e1 = offs[wid + 1];
            float acc[8] = {};
            int e = e0;
            for (; e + 32 <= e1; e += 32) {
                int c0 = ccol[e + g];
                int c1 = ccol[e + 8 + g];
                int c2 = ccol[e + 16 + g];
                int c3 = ccol[e + 24 + g];
                half8 v0 = *(const half8*)(src + (long long)c0 * CLS + sl * 8);
                half8 v1 = *(const half8*)(src + (long long)c1 * CLS + sl * 8);
                half8 v2 = *(const half8*)(src + (long long)c2 * CLS + sl * 8);
                half8 v3 = *(const half8*)(src + (long long)c3 * CLS + sl * 8);
#pragma unroll
                for (int j = 0; j < 8; j++)
                    acc[j] += ((float)v0[j] + (float)v1[j]) + ((float)v2[j] + (float)v3[j]);
            }
            if (e + 16 <= e1) {
                int c0 = ccol[e + g];
                int c1 = ccol[e + 8 + g];
                half8 v0 = *(const half8*)(src + (long long)c0 * CLS + sl * 8);
                half8 v1 = *(const half8*)(src + (long long)c1 * CLS + sl * 8);
#pragma unroll
                for (int j = 0; j < 8; j++) acc[j] += (float)v0[j] + (float)v1[j];
                e += 16;
            }
            if (e + 8 <= e1) {
                int c0 = ccol[e + g];
                half8 v0 = *(const half8*)(src + (long long)c0 * CLS + sl * 8);
#pragma unroll
                for (int j = 0; j < 8; j++) acc[j] += (float)v0[j];
                e += 8;
            }
            if (e < e1) {
                int idx = e + g;
                if (idx < e1) {
                    int c = ccol[idx];
                    half8 v = *(const half8*)(src + (long long)c * CLS + sl * 8);
#pragma unroll
                    for (int j = 0; j < 8; j++) acc[j] += (float)v[j];
                }
            }
            // reduce across the 8 edge subgroups (lanes with same sl)
#pragma unroll
            for (int j = 0; j < 8; j++) {
                acc[j] += __shfl_xor(acc[j], 8);
                acc[j] += __shfl_xor(acc[j], 16);
                acc[j] += __shfl_xor(acc[j], 32);
            }

            float dr = dinv[wid];
            half8 hh = *(const half8*)(h + (long long)wid * CLS + sl * 8);
            float o[8];
#pragma unroll
            for (int j = 0; j < 8; j++) o[j] = 0.9f * dr * acc[j] + 0.1f * (float)hh[j];

            if (!last) {
                if (g == 0) {
                    half8 ov;
#pragma unroll
                    for (int j = 0; j < 8; j++) ov[j] = (_Float16)(dr * o[j]);
                    *(half8*)(dst + (long long)wid * CLS + sl * 8) = ov;
                }
            } else {
                float m = o[0];
#pragma unroll
                for (int j = 1; j < 8; j++) m = fmaxf(m, o[j]);
                m = fmaxf(m, __shfl_xor(m, 1));
                m = fmaxf(m, __shfl_xor(m, 2));
                m = fmaxf(m, __shfl_xor(m, 4));
                float s = 0.f;
#pragma unroll
                for (int j = 0; j < 8; j++) s += expf(o[j] - m);
                s += __shfl_xor(s, 1);
                s += __shfl_xor(s, 2);
                s += __shfl_xor(s, 4);
                float ls = logf(s);
                if (g == 0) {
                    float4 ov0 = make_float4(o[0] - m - ls, o[1] - m - ls, o[2] - m - ls, o[3] - m - ls);
                    float4 ov1 = make_float4(o[4] - m - ls, o[5] - m - ls, o[6] - m - ls, o[7] - m - ls);
                    *(float4*)(out + (long long)wid * CLS + sl * 8) = ov0;
                    *(float4*)(out + (long long)wid * CLS + sl * 8 + 4) = ov1;
                }
            }
        }
        if (!last) gg.sync();
    }
}

extern "C" void kernel_launch(void* const* d_in, const int* in_sizes, int n_in,
                              void* d_out, int out_size, void* d_ws, size_t ws_size,
                              hipStream_t stream) {
    const float* x  = (const float*)d_in[0];
    const void*  ei = d_in[1];
    const float* W1 = (const float*)d_in[2];
    const float* b1 = (const float*)d_in[3];
    const float* W2 = (const float*)d_in[4];
    const float* b2 = (const float*)d_in[5];
    float* out = (float*)d_out;

    char* p = (char*)d_ws;
    size_t off = 0;
    auto alloc = [&](size_t bytes) {
        char* q = p + off;
        off = (off + bytes + 255) & ~(size_t)255;
        return q;
    };
    int*      flag   = (int*)alloc(16);
    float*    dinv   = (float*)alloc((size_t)N_NODES * 4);
    int*      offs   = (int*)alloc((size_t)(N_NODES + 1) * 4);
    int*      bcntR  = (int*)alloc((NBUCK + 1) * 4);
    int*      bcntC  = (int*)alloc((NBUCK + 1) * 4);
    int*      bbaseR = (int*)alloc((NBUCK + 1) * 4);
    int*      bbaseC = (int*)alloc((NBUCK + 1) * 4);
    int*      cbase  = (int*)alloc((NBUCK + 1) * 4);
    int*      histR  = (int*)alloc((size_t)NCHUNK * NBUCK * 4);
    int*      histC  = (int*)alloc((size_t)NCHUNK * NBUCK * 4);
    int*      baseR  = (int*)alloc((size_t)NCHUNK * NBUCK * 4);
    int*      baseC  = (int*)alloc((size_t)NCHUNK * NBUCK * 4);
    unsigned* pairs  = (unsigned*)alloc((size_t)N_EDGES * 4);
    int*      cvals  = (int*)alloc((size_t)N_EDGES * 4);
    int*      ccol   = (int*)alloc(((size_t)N_EDGES + N_NODES + 64) * 4);
    _Float16* h      = (_Float16*)alloc((size_t)N_NODES * CLS * 2);
    _Float16* s0     = (_Float16*)alloc((size_t)N_NODES * CLS * 2);
    _Float16* bufA   = (_Float16*)alloc((size_t)N_NODES * CLS * 2);
    _Float16* bufB   = (_Float16*)alloc((size_t)N_NODES * CLS * 2);
    _Float16* h1     = (_Float16*)alloc((size_t)N_NODES * HID * 2);
    _Float16* W1T    = (_Float16*)alloc((size_t)HID * FEAT * 2);
    _Float16* W2T    = (_Float16*)alloc((size_t)CLS * HID * 2);
    (void)ws_size;

    // graph build (3-phase radix: hist -> scans -> place; then per-bucket CSR)
    k_detect<<<1, 256, 0, stream>>>((const unsigned*)ei, flag, bcntR, bcntC);
    k_bhist<<<NCHUNK, 256, 0, stream>>>(ei, flag, bcntR, bcntC, histR, histC);
    k_bscan<<<1, 64, 0, stream>>>(bcntR, bcntC, bbaseR, bbaseC, cbase, offs);
    k_bscan2<<<2 * NBUCK, 256, 0, stream>>>(histR, bbaseR, baseR, histC, bbaseC, baseC);
    k_binA<<<NCHUNK, 256, 0, stream>>>(ei, flag, baseR, baseC, pairs, cvals);
    k_bins<<<2 * NBUCK, 1024, 0, stream>>>(cvals, bbaseC, dinv, pairs, bbaseR, cbase, offs, ccol);

    // dense layers (fp16 MFMA)
    k_cvtW<<<512, 256, 0, stream>>>(W1, W2, W1T, W2T);
    k_gemm1<<<(N_NODES + 127) / 128, 512, 0, stream>>>(x, W1T, b1, h1, N_NODES);
    k_gemm2<<<(N_NODES + 255) / 256, 512, 0, stream>>>(h1, W2T, b2, dinv, h, s0, N_NODES);

    // fused propagation: one cooperative launch, grid.sync between hops
    int blocksPerCU = 0;
    hipOccupancyMaxActiveBlocksPerMultiprocessor(&blocksPerCU, k_prop_all, 256, 0);
    if (blocksPerCU < 1) blocksPerCU = 1;
    hipDeviceProp_t props;
    int dev = 0;
    hipGetDevice(&dev);
    hipGetDeviceProperties(&props, dev);
    int gridBlocks = blocksPerCU * props.multiProcessorCount;
    int maxUseful = (N_NODES + 3) / 4;  // never more blocks than nodes/4
    if (gridBlocks > maxUseful) gridBlocks = maxUseful;
    int nwaves = gridBlocks * 4;
    void* args[] = {(void*)&ccol, (void*)&offs, (void*)&dinv, (void*)&s0,
                    (void*)&h, (void*)&bufA, (void*)&bufB, (void*)&out,
                    (void*)&nwaves};
    hipLaunchCooperativeKernel((const void*)k_prop_all, dim3(gridBlocks), dim3(256),
                               args, 0, stream);
}

// Round 11
// 1013.019 us; speedup vs baseline: 1.8974x; 1.8974x over previous
//
#include <hip/hip_runtime.h>
#include <hip/hip_bf16.h>
#include <math.h>

#define N_NODES 100000
#define N_EDGES 3200000
#define FEAT 512
#define HID 256
#define CLS 64
#define K_ITER 10
#define NBUCK 196            // ceil(100000 / 512) node buckets of width 512
#define BSH 9                // bucket = r >> 9
#define CH 16384             // edges per chunk
#define NCHUNK 196           // ceil(N_EDGES / CH)
#define SLICE 25000          // source-slice width (3.2 MB of fp16 rows < 4 MB L2)

typedef _Float16 half8 __attribute__((ext_vector_type(8)));
typedef float f32x4 __attribute__((ext_vector_type(4)));

// ---------- edge index access (int32 or int64, detected at runtime) ----------
__device__ __forceinline__ int edge_at(const void* e, int is64, long long idx) {
    return is64 ? (int)((const long long*)e)[idx] : ((const int*)e)[idx];
}

__global__ void k_detect(const unsigned* __restrict__ e, int* __restrict__ flag,
                         int* __restrict__ bcntR, int* __restrict__ bcntC) {
    __shared__ unsigned s[256];
    unsigned v = 0;
    for (int i = threadIdx.x; i < 4096; i += 256) v |= e[2 * i + 1];
    s[threadIdx.x] = v;
    __syncthreads();
    for (int off = 128; off; off >>= 1) {
        if (threadIdx.x < off) s[threadIdx.x] |= s[threadIdx.x + off];
        __syncthreads();
    }
    if (threadIdx.x == 0) flag[0] = (s[0] == 0) ? 1 : 0;
    if (threadIdx.x < NBUCK) { bcntR[threadIdx.x] = 0; bcntC[threadIdx.x] = 0; }
}

// ---------- phase 1: per-chunk bucket histograms (r and c) ----------
__global__ __launch_bounds__(256) void k_bhist(const void* __restrict__ e,
                                               const int* __restrict__ flag,
                                               int* __restrict__ bcntR,
                                               int* __restrict__ bcntC,
                                               int* __restrict__ histR,
                                               int* __restrict__ histC) {
    __shared__ int lhR[NBUCK], lhC[NBUCK];
    for (int i = threadIdx.x; i < NBUCK; i += 256) { lhR[i] = 0; lhC[i] = 0; }
    __syncthreads();
    int is64 = flag[0];
    const int ch = blockIdx.x;
    long long base = (long long)ch * CH;
    for (int j = threadIdx.x; j < CH; j += 256) {
        long long i = base + j;
        if (i < N_EDGES) {
            int r = edge_at(e, is64, i);
            int c = edge_at(e, is64, (long long)N_EDGES + i);
            atomicAdd(&lhR[r >> BSH], 1);
            atomicAdd(&lhC[c >> BSH], 1);
        }
    }
    __syncthreads();
    for (int i = threadIdx.x; i < NBUCK; i += 256) {
        histR[ch * NBUCK + i] = lhR[i];
        histC[ch * NBUCK + i] = lhC[i];
        if (lhR[i]) atomicAdd(&bcntR[i], lhR[i]);
        if (lhC[i]) atomicAdd(&bcntC[i], lhC[i]);
    }
}

// ---------- phase 2a: bucket base scan (196 entries; trivial serial) ----------
__global__ void k_bscan(const int* __restrict__ bcntR, const int* __restrict__ bcntC,
                        int* __restrict__ bbaseR, int* __restrict__ bbaseC,
                        int* __restrict__ cbase, int* __restrict__ offs) {
    if (threadIdx.x == 0) {
        int accE = 0, accC = 0, accCv = 0;
        for (int b = 0; b < NBUCK; b++) {
            bbaseR[b] = accE;
            bbaseC[b] = accCv;
            cbase[b] = accC;
            int nb0 = b << BSH;
            int nn = (N_NODES - nb0 < 512) ? (N_NODES - nb0) : 512;
            accE += bcntR[b];
            accCv += bcntC[b];
            accC += bcntR[b] + nn;
        }
        bbaseR[NBUCK] = accE;
        bbaseC[NBUCK] = accCv;
        cbase[NBUCK] = accC;
        offs[N_NODES] = accC;
    }
}

// ---------- phase 2b: per-(chunk,bucket) bases (scan over chunks) ----------
__global__ __launch_bounds__(256) void k_bscan2(const int* __restrict__ histR,
                                                const int* __restrict__ bbaseR,
                                                int* __restrict__ baseR,
                                                const int* __restrict__ histC,
                                                const int* __restrict__ bbaseC,
                                                int* __restrict__ baseC) {
    __shared__ int s[256];
    const int t = threadIdx.x;
    const int* hist;
    const int* bb;
    int* bout;
    int b;
    if (blockIdx.x < NBUCK) { hist = histR; bb = bbaseR; bout = baseR; b = blockIdx.x; }
    else { hist = histC; bb = bbaseC; bout = baseC; b = blockIdx.x - NBUCK; }
    int v = (t < NCHUNK) ? hist[t * NBUCK + b] : 0;
    s[t] = v;
    __syncthreads();
    for (int off = 1; off < 256; off <<= 1) {
        int a = (t >= off) ? s[t - off] : 0;
        __syncthreads();
        s[t] += a;
        __syncthreads();
    }
    if (t < NCHUNK) bout[t * NBUCK + b] = bb[b] + s[t] - v;
}

// ---------- phase 3: place edges into bucket-contiguous runs (no global atomics) ----------
// pairs entry (r-binned): (c << 9) | (r & 511)   [26 bits used]
__global__ __launch_bounds__(256) void k_binA(const void* __restrict__ e,
                                              const int* __restrict__ flag,
                                              const int* __restrict__ baseR,
                                              const int* __restrict__ baseC,
                                              unsigned* __restrict__ pairs,
                                              int* __restrict__ cvals) {
    __shared__ int lbR[NBUCK], lcR[NBUCK], lbC[NBUCK], lcC[NBUCK];
    const int ch = blockIdx.x;
    for (int i = threadIdx.x; i < NBUCK; i += 256) {
        lbR[i] = baseR[ch * NBUCK + i];
        lcR[i] = 0;
        lbC[i] = baseC[ch * NBUCK + i];
        lcC[i] = 0;
    }
    __syncthreads();
    int is64 = flag[0];
    long long base = (long long)ch * CH;
    for (int j = threadIdx.x; j < CH; j += 256) {
        long long i = base + j;
        if (i < N_EDGES) {
            int r = edge_at(e, is64, i);
            int c = edge_at(e, is64, (long long)N_EDGES + i);
            int b = r >> BSH;
            int pos = atomicAdd(&lcR[b], 1);
            pairs[(long long)lbR[b] + pos] = ((unsigned)c << 9) | (unsigned)(r & 511);
            int bc = c >> BSH;
            int posc = atomicAdd(&lcC[bc], 1);
            cvals[(long long)lbC[bc] + posc] = c;
        }
    }
}

// ---------- merged per-bucket pass: deg/dinv (0..195) + slice-sorted CSR (196..391) ----------
// CSR part additionally sub-sorts each node's edges by source slice (c / SLICE),
// emitting offs2[node] = int4 of the 4 sub-segment starts.
__global__ __launch_bounds__(1024) void k_bins(const int* __restrict__ cvals,
                                               const int* __restrict__ bbaseC,
                                               float* __restrict__ dinv,
                                               const unsigned* __restrict__ pairs,
                                               const int* __restrict__ bbaseR,
                                               const int* __restrict__ cbase,
                                               int* __restrict__ offs,
                                               int4* __restrict__ offs2,
                                               int* __restrict__ ccol) {
    __shared__ int cnt4[2048], cur4[2048], s[512];
    const int t = threadIdx.x;
    if (blockIdx.x < NBUCK) {
        // degree count over c occurrences
        const int b = blockIdx.x;
        const int nb0 = b << BSH;
        const int nn = (N_NODES - nb0 < 512) ? (N_NODES - nb0) : 512;
        if (t < 512) cnt4[t] = 1;  // self loop
        __syncthreads();
        const int e0 = bbaseC[b], e1 = bbaseC[b + 1];
        for (int i = e0 + t; i < e1; i += 1024) {
            atomicAdd(&cnt4[cvals[i] - nb0], 1);
        }
        __syncthreads();
        if (t < nn) dinv[nb0 + t] = rsqrtf((float)cnt4[t]);
        return;
    }
    // CSR build with per-slice sub-segments
    const int b = blockIdx.x - NBUCK;
    const int nb0 = b << BSH;
    const int nn = (N_NODES - nb0 < 512) ? (N_NODES - nb0) : 512;
    for (int i = t; i < 2048; i += 1024) cnt4[i] = 0;
    __syncthreads();
    if (t < nn) cnt4[t * 4 + (nb0 + t) / SLICE] = 1;  // self loop
    __syncthreads();
    const int e0 = bbaseR[b], e1 = bbaseR[b + 1];
    for (int i = e0 + t; i < e1; i += 1024) {
        unsigned p = pairs[i];
        int r = (int)(p & 511u);
        int c = (int)(p >> 9);
        atomicAdd(&cnt4[r * 4 + c / SLICE], 1);
    }
    __syncthreads();
    // exclusive scan of per-node totals
    int tot = 0;
    if (t < 512)
        tot = cnt4[t * 4] + cnt4[t * 4 + 1] + cnt4[t * 4 + 2] + cnt4[t * 4 + 3];
    if (t < 512) s[t] = tot;
    __syncthreads();
    for (int off = 1; off < 512; off <<= 1) {
        int a = 0;
        if (t < 512 && t >= off) a = s[t - off];
        __syncthreads();
        if (t < 512) s[t] += a;
        __syncthreads();
    }
    const int cb = cbase[b];
    if (t < 512) {
        int a0 = cb + s[t] - tot;
        int a1 = a0 + cnt4[t * 4 + 0];
        int a2 = a1 + cnt4[t * 4 + 1];
        int a3 = a2 + cnt4[t * 4 + 2];
        cur4[t * 4 + 0] = a0;
        cur4[t * 4 + 1] = a1;
        cur4[t * 4 + 2] = a2;
        cur4[t * 4 + 3] = a3;
        if (t < nn) {
            int node = nb0 + t;
            offs[node] = a0;
            offs2[node] = make_int4(a0, a1, a2, a3);
            int sb = node / SLICE;
            int pos = cur4[t * 4 + sb];
            cur4[t * 4 + sb] = pos + 1;
            ccol[pos] = node;  // self loop entry
        }
    }
    __syncthreads();
    for (int i = e0 + t; i < e1; i += 1024) {
        unsigned p = pairs[i];
        int r = (int)(p & 511u);
        int c = (int)(p >> 9);
        int pos = atomicAdd(&cur4[r * 4 + c / SLICE], 1);
        ccol[pos] = c;
    }
}

// ---------- weight transpose + fp16 convert ----------
__global__ void k_cvtW(const float* __restrict__ W1, const float* __restrict__ W2,
                       _Float16* __restrict__ W1T, _Float16* __restrict__ W2T) {
    int i = blockIdx.x * 256 + threadIdx.x;
    if (i < 256 * 512) {
        int n = i >> 9, k = i & 511;
        W1T[i] = (_Float16)W1[k * 256 + n];
    }
    if (i < 64 * 256) {
        int n = i >> 8, k = i & 255;
        W2T[i] = (_Float16)W2[k * 64 + n];
    }
}

// swizzle helper: physical granule for (row, logical granule)
__device__ __forceinline__ int swz(int row, int g) {
    return g ^ (row & 3) ^ ((row >> 2) & 3);
}

// ---------- GEMM1: h1[M][256](fp16) = relu(x[M][512](fp32) @ W1 + b1) ----------
__global__ __launch_bounds__(512) void k_gemm1(const float* __restrict__ A,
                                               const _Float16* __restrict__ BT,
                                               const float* __restrict__ bias,
                                               _Float16* __restrict__ C, int M) {
    __shared__ __align__(16) char lds[8192 + 16384];
    const int t = threadIdx.x;
    const int wid = t >> 6, lane = t & 63;
    const int wr = wid >> 2, wc = wid & 3;
    const int srow = t >> 2, sg = t & 3;
    const int fr = lane & 15, fg = lane >> 4;
    const long long by = blockIdx.x;

    f32x4 acc[4][4] = {};
    const long long arow = by * 128 + srow;
    const bool avalid = (arow < M);
    const float* ap0 = A + arow * FEAT + sg * 8;

    for (int kt = 0; kt < FEAT; kt += 32) {
        float4 a0 = make_float4(0.f, 0.f, 0.f, 0.f), a1 = a0;
        if (avalid) {
            const float* ap = ap0 + kt;
            a0 = *(const float4*)ap;
            a1 = *(const float4*)(ap + 4);
        }
        half8 ah;
        ah[0] = (_Float16)a0.x; ah[1] = (_Float16)a0.y;
        ah[2] = (_Float16)a0.z; ah[3] = (_Float16)a0.w;
        ah[4] = (_Float16)a1.x; ah[5] = (_Float16)a1.y;
        ah[6] = (_Float16)a1.z; ah[7] = (_Float16)a1.w;
        *(half8*)(lds + srow * 64 + swz(srow, sg) * 16) = ah;
#pragma unroll
        for (int rep = 0; rep < 2; rep++) {
            int brow = rep * 128 + srow;
            half8 bh = *(const half8*)(BT + brow * FEAT + kt + sg * 8);
            *(half8*)(lds + 8192 + brow * 64 + swz(brow, sg) * 16) = bh;
        }
        __syncthreads();

        half8 af[4], bf[4];
#pragma unroll
        for (int mi = 0; mi < 4; mi++) {
            int r = wr * 64 + mi * 16 + fr;
            af[mi] = *(const half8*)(lds + r * 64 + swz(r, fg) * 16);
        }
#pragma unroll
        for (int nj = 0; nj < 4; nj++) {
            int r = wc * 64 + nj * 16 + fr;
            bf[nj] = *(const half8*)(lds + 8192 + r * 64 + swz(r, fg) * 16);
        }
#pragma unroll
        for (int mi = 0; mi < 4; mi++)
#pragma unroll
            for (int nj = 0; nj < 4; nj++)
                acc[mi][nj] = __builtin_amdgcn_mfma_f32_16x16x32_f16(af[mi], bf[nj], acc[mi][nj], 0, 0, 0);
        __syncthreads();
    }

#pragma unroll
    for (int mi = 0; mi < 4; mi++) {
#pragma unroll
        for (int nj = 0; nj < 4; nj++) {
            int col = wc * 64 + nj * 16 + fr;
            float bv = bias[col];
#pragma unroll
            for (int r = 0; r < 4; r++) {
                long long row = by * 128 + wr * 64 + mi * 16 + fg * 4 + r;
                if (row < M) {
                    float v = fmaxf(acc[mi][nj][r] + bv, 0.f);
                    C[row * HID + col] = (_Float16)v;
                }
            }
        }
    }
}

// ---------- GEMM2: h[M][64](fp16), s0[M][64](fp16 = dinv*h) ----------
__global__ __launch_bounds__(512) void k_gemm2(const _Float16* __restrict__ A,
                                               const _Float16* __restrict__ BT,
                                               const float* __restrict__ bias,
                                               const float* __restrict__ dinv,
                                               _Float16* __restrict__ Hout,
                                               _Float16* __restrict__ S0, int M) {
    __shared__ __align__(16) char lds[16384 + 4096];
    const int t = threadIdx.x;
    const int wid = t >> 6, lane = t & 63;
    const int wr = wid >> 1, wc = wid & 1;
    const int srow = t >> 2, sg = t & 3;
    const int fr = lane & 15, fg = lane >> 4;
    const long long bm = blockIdx.x;

    f32x4 acc[4][2] = {};

    for (int kt = 0; kt < HID; kt += 32) {
#pragma unroll
        for (int rep = 0; rep < 2; rep++) {
            int ar = rep * 128 + srow;
            long long grow = bm * 256 + ar;
            if (grow >= M) grow = M - 1;
            half8 ah = *(const half8*)(A + grow * HID + kt + sg * 8);
            *(half8*)(lds + ar * 64 + swz(ar, sg) * 16) = ah;
        }
        if (t < 256) {
            int br = t >> 2;
            half8 bh = *(const half8*)(BT + br * HID + kt + sg * 8);
            *(half8*)(lds + 16384 + br * 64 + swz(br, sg) * 16) = bh;
        }
        __syncthreads();

        half8 af[4], bf[2];
#pragma unroll
        for (int mi = 0; mi < 4; mi++) {
            int r = wr * 64 + mi * 16 + fr;
            af[mi] = *(const half8*)(lds + r * 64 + swz(r, fg) * 16);
        }
#pragma unroll
        for (int nj = 0; nj < 2; nj++) {
            int r = wc * 32 + nj * 16 + fr;
            bf[nj] = *(const half8*)(lds + 16384 + r * 64 + swz(r, fg) * 16);
        }
#pragma unroll
        for (int mi = 0; mi < 4; mi++)
#pragma unroll
            for (int nj = 0; nj < 2; nj++)
                acc[mi][nj] = __builtin_amdgcn_mfma_f32_16x16x32_f16(af[mi], bf[nj], acc[mi][nj], 0, 0, 0);
        __syncthreads();
    }

#pragma unroll
    for (int mi = 0; mi < 4; mi++) {
#pragma unroll
        for (int nj = 0; nj < 2; nj++) {
            int col = wc * 32 + nj * 16 + fr;
            float bv = bias[col];
#pragma unroll
            for (int r = 0; r < 4; r++) {
                long long row = bm * 256 + wr * 64 + mi * 16 + fg * 4 + r;
                if (row < M) {
                    float o = acc[mi][nj][r] + bv;
                    Hout[row * CLS + col] = (_Float16)o;
                    S0[row * CLS + col] = (_Float16)(dinv[row] * o);
                }
            }
        }
    }
}

// ---------- propagation: one wave per node; slice-ordered gathers ----------
// Edges are pre-sorted by source slice; concurrent waves sweep slices in the
// same order, so the active gather set is one 3.2 MB slice (L2-resident).
__global__ __launch_bounds__(256) void k_prop(const int* __restrict__ ccol,
                                              const int* __restrict__ offs,
                                              const int4* __restrict__ offs2,
                                              const float* __restrict__ dinv,
                                              const _Float16* __restrict__ src,
                                              const _Float16* __restrict__ h,
                                              _Float16* __restrict__ dst,
                                              float* __restrict__ out, int last) {
    int wid = (blockIdx.x << 2) + (threadIdx.x >> 6);
    int lane = threadIdx.x & 63;
    if (wid >= N_NODES) return;
    const int g = lane >> 3;
    const int sl = lane & 7;
    const int4 o2 = offs2[wid];
    const int eend = offs[wid + 1];
    int segs[5];
    segs[0] = o2.x; segs[1] = o2.y; segs[2] = o2.z; segs[3] = o2.w; segs[4] = eend;
    float acc[8] = {};
#pragma unroll
    for (int blk = 0; blk < 4; blk++) {
        int e = segs[blk];
        const int bnd = segs[blk + 1];
        for (; e + 16 <= bnd; e += 16) {
            int c0 = ccol[e + g];
            int c1 = ccol[e + 8 + g];
            half8 v0 = *(const half8*)(src + (long long)c0 * CLS + sl * 8);
            half8 v1 = *(const half8*)(src + (long long)c1 * CLS + sl * 8);
#pragma unroll
            for (int j = 0; j < 8; j++) acc[j] += (float)v0[j] + (float)v1[j];
        }
        if (e + 8 <= bnd) {
            int c0 = ccol[e + g];
            half8 v0 = *(const half8*)(src + (long long)c0 * CLS + sl * 8);
#pragma unroll
            for (int j = 0; j < 8; j++) acc[j] += (float)v0[j];
            e += 8;
        }
        if (e < bnd) {
            int idx = e + g;
            if (idx < bnd) {
                int c = ccol[idx];
                half8 v = *(const half8*)(src + (long long)c * CLS + sl * 8);
#pragma unroll
                for (int j = 0; j < 8; j++) acc[j] += (float)v[j];
            }
        }
    }
    // reduce across the 8 edge subgroups (lanes with same sl)
#pragma unroll
    for (int j = 0; j < 8; j++) {
        acc[j] += __shfl_xor(acc[j], 8);
        acc[j] += __shfl_xor(acc[j], 16);
        acc[j] += __shfl_xor(acc[j], 32);
    }

    float dr = dinv[wid];
    half8 hh = *(const half8*)(h + (long long)wid * CLS + sl * 8);
    float o[8];
#pragma unroll
    for (int j = 0; j < 8; j++) o[j] = 0.9f * dr * acc[j] + 0.1f * (float)hh[j];

    if (!last) {
        if (g == 0) {
            half8 ov;
#pragma unroll
            for (int j = 0; j < 8; j++) ov[j] = (_Float16)(dr * o[j]);
            *(half8*)(dst + (long long)wid * CLS + sl * 8) = ov;
        }
    } else {
        float m = o[0];
#pragma unroll
        for (int j = 1; j < 8; j++) m = fmaxf(m, o[j]);
        m = fmaxf(m, __shfl_xor(m, 1));
        m = fmaxf(m, __shfl_xor(m, 2));
        m = fmaxf(m, __shfl_xor(m, 4));
        float s = 0.f;
#pragma unroll
        for (int j = 0; j < 8; j++) s += expf(o[j] - m);
        s += __shfl_xor(s, 1);
        s += __shfl_xor(s, 2);
        s += __shfl_xor(s, 4);
        float ls = logf(s);
        if (g == 0) {
            float4 ov0 = make_float4(o[0] - m - ls, o[1] - m - ls, o[2] - m - ls, o[3] - m - ls);
            float4 ov1 = make_float4(o[4] - m - ls, o[5] - m - ls, o[6] - m - ls, o[7] - m - ls);
            *(float4*)(out + (long long)wid * CLS + sl * 8) = ov0;
            *(float4*)(out + (long long)wid * CLS + sl * 8 + 4) = ov1;
        }
    }
}

extern "C" void kernel_launch(void* const* d_in, const int* in_sizes, int n_in,
                              void* d_out, int out_size, void* d_ws, size_t ws_size,
                              hipStream_t stream) {
    const float* x  = (const float*)d_in[0];
    const void*  ei = d_in[1];
    const float* W1 = (const float*)d_in[2];
    const float* b1 = (const float*)d_in[3];
    const float* W2 = (const float*)d_in[4];
    const float* b2 = (const float*)d_in[5];
    float* out = (float*)d_out;

    char* p = (char*)d_ws;
    size_t off = 0;
    auto alloc = [&](size_t bytes) {
        char* q = p + off;
        off = (off + bytes + 255) & ~(size_t)255;
        return q;
    };
    int*      flag   = (int*)alloc(16);
    float*    dinv   = (float*)alloc((size_t)N_NODES * 4);
    int*      offs   = (int*)alloc((size_t)(N_NODES + 1) * 4);
    int4*     offs2  = (int4*)alloc((size_t)N_NODES * 16);
    int*      bcntR  = (int*)alloc((NBUCK + 1) * 4);
    int*      bcntC  = (int*)alloc((NBUCK + 1) * 4);
    int*      bbaseR = (int*)alloc((NBUCK + 1) * 4);
    int*      bbaseC = (int*)alloc((NBUCK + 1) * 4);
    int*      cbase  = (int*)alloc((NBUCK + 1) * 4);
    int*      histR  = (int*)alloc((size_t)NCHUNK * NBUCK * 4);
    int*      histC  = (int*)alloc((size_t)NCHUNK * NBUCK * 4);
    int*      baseR  = (int*)alloc((size_t)NCHUNK * NBUCK * 4);
    int*      baseC  = (int*)alloc((size_t)NCHUNK * NBUCK * 4);
    unsigned* pairs  = (unsigned*)alloc((size_t)N_EDGES * 4);
    int*      cvals  = (int*)alloc((size_t)N_EDGES * 4);
    int*      ccol   = (int*)alloc(((size_t)N_EDGES + N_NODES + 64) * 4);
    _Float16* h      = (_Float16*)alloc((size_t)N_NODES * CLS * 2);
    _Float16* s0     = (_Float16*)alloc((size_t)N_NODES * CLS * 2);
    _Float16* bufA   = (_Float16*)alloc((size_t)N_NODES * CLS * 2);
    _Float16* bufB   = (_Float16*)alloc((size_t)N_NODES * CLS * 2);
    _Float16* h1     = (_Float16*)alloc((size_t)N_NODES * HID * 2);
    _Float16* W1T    = (_Float16*)alloc((size_t)HID * FEAT * 2);
    _Float16* W2T    = (_Float16*)alloc((size_t)CLS * HID * 2);
    (void)ws_size;

    // graph build (3-phase radix: hist -> scans -> place; then per-bucket CSR)
    k_detect<<<1, 256, 0, stream>>>((const unsigned*)ei, flag, bcntR, bcntC);
    k_bhist<<<NCHUNK, 256, 0, stream>>>(ei, flag, bcntR, bcntC, histR, histC);
    k_bscan<<<1, 64, 0, stream>>>(bcntR, bcntC, bbaseR, bbaseC, cbase, offs);
    k_bscan2<<<2 * NBUCK, 256, 0, stream>>>(histR, bbaseR, baseR, histC, bbaseC, baseC);
    k_binA<<<NCHUNK, 256, 0, stream>>>(ei, flag, baseR, baseC, pairs, cvals);
    k_bins<<<2 * NBUCK, 1024, 0, stream>>>(cvals, bbaseC, dinv, pairs, bbaseR, cbase,
                                           offs, offs2, ccol);

    // dense layers (fp16 MFMA)
    k_cvtW<<<512, 256, 0, stream>>>(W1, W2, W1T, W2T);
    k_gemm1<<<(N_NODES + 127) / 128, 512, 0, stream>>>(x, W1T, b1, h1, N_NODES);
    k_gemm2<<<(N_NODES + 255) / 256, 512, 0, stream>>>(h1, W2T, b2, dinv, h, s0, N_NODES);

    // K propagation steps; final step fuses log_softmax
    const int pgrid = (N_NODES + 3) / 4;
    _Float16* ping[2] = {bufA, bufB};
    for (int it = 0; it < K_ITER; it++) {
        const _Float16* src = (it == 0) ? s0 : ping[(it - 1) & 1];
        _Float16* dst = ping[it & 1];
        k_prop<<<pgrid, 256, 0, stream>>>(ccol, offs, offs2, dinv, src, h, dst, out,
                                          it == K_ITER - 1);
    }
}

// Round 12
// 772.384 us; speedup vs baseline: 2.4885x; 1.3115x over previous
//
#include <hip/hip_runtime.h>
#include <hip/hip_bf16.h>
#include <math.h>

#define N_NODES 100000
#define N_EDGES 3200000
#define FEAT 512
#define HID 256
#define CLS 64
#define K_ITER 10
#define NBUCK 196            // ceil(100000 / 512) node buckets of width 512
#define BSH 9                // bucket = r >> 9
#define CH 16384             // edges per chunk
#define NCHUNK 196           // ceil(N_EDGES / CH)
#define SLICE 25000          // source-slice width (3.2 MB of fp16 rows < 4 MB L2)

typedef _Float16 half8 __attribute__((ext_vector_type(8)));
typedef float f32x4 __attribute__((ext_vector_type(4)));

// ---------- edge index access (int32 or int64, detected at runtime) ----------
__device__ __forceinline__ int edge_at(const void* e, int is64, long long idx) {
    return is64 ? (int)((const long long*)e)[idx] : ((const int*)e)[idx];
}

__global__ void k_detect(const unsigned* __restrict__ e, int* __restrict__ flag,
                         int* __restrict__ bcntR, int* __restrict__ bcntC) {
    __shared__ unsigned s[256];
    unsigned v = 0;
    for (int i = threadIdx.x; i < 4096; i += 256) v |= e[2 * i + 1];
    s[threadIdx.x] = v;
    __syncthreads();
    for (int off = 128; off; off >>= 1) {
        if (threadIdx.x < off) s[threadIdx.x] |= s[threadIdx.x + off];
        __syncthreads();
    }
    if (threadIdx.x == 0) flag[0] = (s[0] == 0) ? 1 : 0;
    if (threadIdx.x < NBUCK) { bcntR[threadIdx.x] = 0; bcntC[threadIdx.x] = 0; }
}

// ---------- phase 1: per-chunk bucket histograms (r and c) ----------
__global__ __launch_bounds__(256) void k_bhist(const void* __restrict__ e,
                                               const int* __restrict__ flag,
                                               int* __restrict__ bcntR,
                                               int* __restrict__ bcntC,
                                               int* __restrict__ histR,
                                               int* __restrict__ histC) {
    __shared__ int lhR[NBUCK], lhC[NBUCK];
    for (int i = threadIdx.x; i < NBUCK; i += 256) { lhR[i] = 0; lhC[i] = 0; }
    __syncthreads();
    int is64 = flag[0];
    const int ch = blockIdx.x;
    long long base = (long long)ch * CH;
    for (int j = threadIdx.x; j < CH; j += 256) {
        long long i = base + j;
        if (i < N_EDGES) {
            int r = edge_at(e, is64, i);
            int c = edge_at(e, is64, (long long)N_EDGES + i);
            atomicAdd(&lhR[r >> BSH], 1);
            atomicAdd(&lhC[c >> BSH], 1);
        }
    }
    __syncthreads();
    for (int i = threadIdx.x; i < NBUCK; i += 256) {
        histR[ch * NBUCK + i] = lhR[i];
        histC[ch * NBUCK + i] = lhC[i];
        if (lhR[i]) atomicAdd(&bcntR[i], lhR[i]);
        if (lhC[i]) atomicAdd(&bcntC[i], lhC[i]);
    }
}

// ---------- phase 2a: bucket base scan (196 entries; trivial serial) ----------
__global__ void k_bscan(const int* __restrict__ bcntR, const int* __restrict__ bcntC,
                        int* __restrict__ bbaseR, int* __restrict__ bbaseC,
                        int* __restrict__ cbase, int* __restrict__ offs) {
    if (threadIdx.x == 0) {
        int accE = 0, accC = 0, accCv = 0;
        for (int b = 0; b < NBUCK; b++) {
            bbaseR[b] = accE;
            bbaseC[b] = accCv;
            cbase[b] = accC;
            int nb0 = b << BSH;
            int nn = (N_NODES - nb0 < 512) ? (N_NODES - nb0) : 512;
            accE += bcntR[b];
            accCv += bcntC[b];
            accC += bcntR[b] + nn;
        }
        bbaseR[NBUCK] = accE;
        bbaseC[NBUCK] = accCv;
        cbase[NBUCK] = accC;
        offs[N_NODES] = accC;
    }
}

// ---------- phase 2b: per-(chunk,bucket) bases (scan over chunks) ----------
__global__ __launch_bounds__(256) void k_bscan2(const int* __restrict__ histR,
                                                const int* __restrict__ bbaseR,
                                                int* __restrict__ baseR,
                                                const int* __restrict__ histC,
                                                const int* __restrict__ bbaseC,
                                                int* __restrict__ baseC) {
    __shared__ int s[256];
    const int t = threadIdx.x;
    const int* hist;
    const int* bb;
    int* bout;
    int b;
    if (blockIdx.x < NBUCK) { hist = histR; bb = bbaseR; bout = baseR; b = blockIdx.x; }
    else { hist = histC; bb = bbaseC; bout = baseC; b = blockIdx.x - NBUCK; }
    int v = (t < NCHUNK) ? hist[t * NBUCK + b] : 0;
    s[t] = v;
    __syncthreads();
    for (int off = 1; off < 256; off <<= 1) {
        int a = (t >= off) ? s[t - off] : 0;
        __syncthreads();
        s[t] += a;
        __syncthreads();
    }
    if (t < NCHUNK) bout[t * NBUCK + b] = bb[b] + s[t] - v;
}

// ---------- phase 3: place edges into bucket-contiguous runs (no global atomics) ----------
// pairs entry (r-binned): (c << 9) | (r & 511)   [26 bits used]
__global__ __launch_bounds__(256) void k_binA(const void* __restrict__ e,
                                              const int* __restrict__ flag,
                                              const int* __restrict__ baseR,
                                              const int* __restrict__ baseC,
                                              unsigned* __restrict__ pairs,
                                              int* __restrict__ cvals) {
    __shared__ int lbR[NBUCK], lcR[NBUCK], lbC[NBUCK], lcC[NBUCK];
    const int ch = blockIdx.x;
    for (int i = threadIdx.x; i < NBUCK; i += 256) {
        lbR[i] = baseR[ch * NBUCK + i];
        lcR[i] = 0;
        lbC[i] = baseC[ch * NBUCK + i];
        lcC[i] = 0;
    }
    __syncthreads();
    int is64 = flag[0];
    long long base = (long long)ch * CH;
    for (int j = threadIdx.x; j < CH; j += 256) {
        long long i = base + j;
        if (i < N_EDGES) {
            int r = edge_at(e, is64, i);
            int c = edge_at(e, is64, (long long)N_EDGES + i);
            int b = r >> BSH;
            int pos = atomicAdd(&lcR[b], 1);
            pairs[(long long)lbR[b] + pos] = ((unsigned)c << 9) | (unsigned)(r & 511);
            int bc = c >> BSH;
            int posc = atomicAdd(&lcC[bc], 1);
            cvals[(long long)lbC[bc] + posc] = c;
        }
    }
}

// ---------- merged per-bucket pass: deg/dinv (0..195) + slice-ordered CSR (196..391) ----------
// Each node's edges are placed sorted by source slice (c / SLICE) within its
// unchanged CSR segment; prop reads the segment linearly (order-only change).
__global__ __launch_bounds__(1024) void k_bins(const int* __restrict__ cvals,
                                               const int* __restrict__ bbaseC,
                                               float* __restrict__ dinv,
                                               const unsigned* __restrict__ pairs,
                                               const int* __restrict__ bbaseR,
                                               const int* __restrict__ cbase,
                                               int* __restrict__ offs,
                                               int* __restrict__ ccol) {
    __shared__ int cnt4[2048], cur4[2048], s[512];
    const int t = threadIdx.x;
    if (blockIdx.x < NBUCK) {
        // degree count over c occurrences
        const int b = blockIdx.x;
        const int nb0 = b << BSH;
        const int nn = (N_NODES - nb0 < 512) ? (N_NODES - nb0) : 512;
        if (t < 512) cnt4[t] = 1;  // self loop
        __syncthreads();
        const int e0 = bbaseC[b], e1 = bbaseC[b + 1];
        for (int i = e0 + t; i < e1; i += 1024) {
            atomicAdd(&cnt4[cvals[i] - nb0], 1);
        }
        __syncthreads();
        if (t < nn) dinv[nb0 + t] = rsqrtf((float)cnt4[t]);
        return;
    }
    // CSR build, slice-sorted placement within each node's segment
    const int b = blockIdx.x - NBUCK;
    const int nb0 = b << BSH;
    const int nn = (N_NODES - nb0 < 512) ? (N_NODES - nb0) : 512;
    for (int i = t; i < 2048; i += 1024) cnt4[i] = 0;
    __syncthreads();
    if (t < nn) cnt4[t * 4 + (nb0 + t) / SLICE] = 1;  // self loop
    __syncthreads();
    const int e0 = bbaseR[b], e1 = bbaseR[b + 1];
    for (int i = e0 + t; i < e1; i += 1024) {
        unsigned p = pairs[i];
        int r = (int)(p & 511u);
        int c = (int)(p >> 9);
        atomicAdd(&cnt4[r * 4 + c / SLICE], 1);
    }
    __syncthreads();
    // exclusive scan of per-node totals
    int tot = 0;
    if (t < 512)
        tot = cnt4[t * 4] + cnt4[t * 4 + 1] + cnt4[t * 4 + 2] + cnt4[t * 4 + 3];
    if (t < 512) s[t] = tot;
    __syncthreads();
    for (int off = 1; off < 512; off <<= 1) {
        int a = 0;
        if (t < 512 && t >= off) a = s[t - off];
        __syncthreads();
        if (t < 512) s[t] += a;
        __syncthreads();
    }
    const int cb = cbase[b];
    if (t < 512) {
        int a0 = cb + s[t] - tot;
        cur4[t * 4 + 0] = a0;
        cur4[t * 4 + 1] = a0 + cnt4[t * 4 + 0];
        cur4[t * 4 + 2] = a0 + cnt4[t * 4 + 0] + cnt4[t * 4 + 1];
        cur4[t * 4 + 3] = a0 + cnt4[t * 4 + 0] + cnt4[t * 4 + 1] + cnt4[t * 4 + 2];
        if (t < nn) {
            int node = nb0 + t;
            offs[node] = a0;
            int sb = node / SLICE;
            int pos = cur4[t * 4 + sb];
            cur4[t * 4 + sb] = pos + 1;
            ccol[pos] = node;  // self loop entry
        }
    }
    __syncthreads();
    for (int i = e0 + t; i < e1; i += 1024) {
        unsigned p = pairs[i];
        int r = (int)(p & 511u);
        int c = (int)(p >> 9);
        int pos = atomicAdd(&cur4[r * 4 + c / SLICE], 1);
        ccol[pos] = c;
    }
}

// ---------- weight transpose + fp16 convert ----------
__global__ void k_cvtW(const float* __restrict__ W1, const float* __restrict__ W2,
                       _Float16* __restrict__ W1T, _Float16* __restrict__ W2T) {
    int i = blockIdx.x * 256 + threadIdx.x;
    if (i < 256 * 512) {
        int n = i >> 9, k = i & 511;
        W1T[i] = (_Float16)W1[k * 256 + n];
    }
    if (i < 64 * 256) {
        int n = i >> 8, k = i & 255;
        W2T[i] = (_Float16)W2[k * 64 + n];
    }
}

// swizzle helper: physical granule for (row, logical granule)
__device__ __forceinline__ int swz(int row, int g) {
    return g ^ (row & 3) ^ ((row >> 2) & 3);
}

// ---------- GEMM1: h1[M][256](fp16) = relu(x[M][512](fp32) @ W1 + b1) ----------
__global__ __launch_bounds__(512) void k_gemm1(const float* __restrict__ A,
                                               const _Float16* __restrict__ BT,
                                               const float* __restrict__ bias,
                                               _Float16* __restrict__ C, int M) {
    __shared__ __align__(16) char lds[8192 + 16384];
    const int t = threadIdx.x;
    const int wid = t >> 6, lane = t & 63;
    const int wr = wid >> 2, wc = wid & 3;
    const int srow = t >> 2, sg = t & 3;
    const int fr = lane & 15, fg = lane >> 4;
    const long long by = blockIdx.x;

    f32x4 acc[4][4] = {};
    const long long arow = by * 128 + srow;
    const bool avalid = (arow < M);
    const float* ap0 = A + arow * FEAT + sg * 8;

    for (int kt = 0; kt < FEAT; kt += 32) {
        float4 a0 = make_float4(0.f, 0.f, 0.f, 0.f), a1 = a0;
        if (avalid) {
            const float* ap = ap0 + kt;
            a0 = *(const float4*)ap;
            a1 = *(const float4*)(ap + 4);
        }
        half8 ah;
        ah[0] = (_Float16)a0.x; ah[1] = (_Float16)a0.y;
        ah[2] = (_Float16)a0.z; ah[3] = (_Float16)a0.w;
        ah[4] = (_Float16)a1.x; ah[5] = (_Float16)a1.y;
        ah[6] = (_Float16)a1.z; ah[7] = (_Float16)a1.w;
        *(half8*)(lds + srow * 64 + swz(srow, sg) * 16) = ah;
#pragma unroll
        for (int rep = 0; rep < 2; rep++) {
            int brow = rep * 128 + srow;
            half8 bh = *(const half8*)(BT + brow * FEAT + kt + sg * 8);
            *(half8*)(lds + 8192 + brow * 64 + swz(brow, sg) * 16) = bh;
        }
        __syncthreads();

        half8 af[4], bf[4];
#pragma unroll
        for (int mi = 0; mi < 4; mi++) {
            int r = wr * 64 + mi * 16 + fr;
            af[mi] = *(const half8*)(lds + r * 64 + swz(r, fg) * 16);
        }
#pragma unroll
        for (int nj = 0; nj < 4; nj++) {
            int r = wc * 64 + nj * 16 + fr;
            bf[nj] = *(const half8*)(lds + 8192 + r * 64 + swz(r, fg) * 16);
        }
#pragma unroll
        for (int mi = 0; mi < 4; mi++)
#pragma unroll
            for (int nj = 0; nj < 4; nj++)
                acc[mi][nj] = __builtin_amdgcn_mfma_f32_16x16x32_f16(af[mi], bf[nj], acc[mi][nj], 0, 0, 0);
        __syncthreads();
    }

#pragma unroll
    for (int mi = 0; mi < 4; mi++) {
#pragma unroll
        for (int nj = 0; nj < 4; nj++) {
            int col = wc * 64 + nj * 16 + fr;
            float bv = bias[col];
#pragma unroll
            for (int r = 0; r < 4; r++) {
                long long row = by * 128 + wr * 64 + mi * 16 + fg * 4 + r;
                if (row < M) {
                    float v = fmaxf(acc[mi][nj][r] + bv, 0.f);
                    C[row * HID + col] = (_Float16)v;
                }
            }
        }
    }
}

// ---------- GEMM2: h[M][64](fp16), s0[M][64](fp16 = dinv*h) ----------
__global__ __launch_bounds__(512) void k_gemm2(const _Float16* __restrict__ A,
                                               const _Float16* __restrict__ BT,
                                               const float* __restrict__ bias,
                                               const float* __restrict__ dinv,
                                               _Float16* __restrict__ Hout,
                                               _Float16* __restrict__ S0, int M) {
    __shared__ __align__(16) char lds[16384 + 4096];
    const int t = threadIdx.x;
    const int wid = t >> 6, lane = t & 63;
    const int wr = wid >> 1, wc = wid & 1;
    const int srow = t >> 2, sg = t & 3;
    const int fr = lane & 15, fg = lane >> 4;
    const long long bm = blockIdx.x;

    f32x4 acc[4][2] = {};

    for (int kt = 0; kt < HID; kt += 32) {
#pragma unroll
        for (int rep = 0; rep < 2; rep++) {
            int ar = rep * 128 + srow;
            long long grow = bm * 256 + ar;
            if (grow >= M) grow = M - 1;
            half8 ah = *(const half8*)(A + grow * HID + kt + sg * 8);
            *(half8*)(lds + ar * 64 + swz(ar, sg) * 16) = ah;
        }
        if (t < 256) {
            int br = t >> 2;
            half8 bh = *(const half8*)(BT + br * HID + kt + sg * 8);
            *(half8*)(lds + 16384 + br * 64 + swz(br, sg) * 16) = bh;
        }
        __syncthreads();

        half8 af[4], bf[2];
#pragma unroll
        for (int mi = 0; mi < 4; mi++) {
            int r = wr * 64 + mi * 16 + fr;
            af[mi] = *(const half8*)(lds + r * 64 + swz(r, fg) * 16);
        }
#pragma unroll
        for (int nj = 0; nj < 2; nj++) {
            int r = wc * 32 + nj * 16 + fr;
            bf[nj] = *(const half8*)(lds + 16384 + r * 64 + swz(r, fg) * 16);
        }
#pragma unroll
        for (int mi = 0; mi < 4; mi++)
#pragma unroll
            for (int nj = 0; nj < 2; nj++)
                acc[mi][nj] = __builtin_amdgcn_mfma_f32_16x16x32_f16(af[mi], bf[nj], acc[mi][nj], 0, 0, 0);
        __syncthreads();
    }

#pragma unroll
    for (int mi = 0; mi < 4; mi++) {
#pragma unroll
        for (int nj = 0; nj < 2; nj++) {
            int col = wc * 32 + nj * 16 + fr;
            float bv = bias[col];
#pragma unroll
            for (int r = 0; r < 4; r++) {
                long long row = bm * 256 + wr * 64 + mi * 16 + fg * 4 + r;
                if (row < M) {
                    float o = acc[mi][nj][r] + bv;
                    Hout[row * CLS + col] = (_Float16)o;
                    S0[row * CLS + col] = (_Float16)(dinv[row] * o);
                }
            }
        }
    }
}

// ---------- propagation: one wave per node; 8 rows per gather instruction ----------
// lane = (g = lane>>3 edge subgroup 0..7, sl = lane&7 class-octet). 32-deep main
// loop keeps 4 gather instructions (32 row transactions) in flight per wave.
// Edge lists are slice-sorted (order-only) to concentrate the gather set in L2.
__global__ __launch_bounds__(256) void k_prop(const int* __restrict__ ccol,
                                              const int* __restrict__ offs,
                                              const float* __restrict__ dinv,
                                              const _Float16* __restrict__ src,
                                              const _Float16* __restrict__ h,
                                              _Float16* __restrict__ dst,
                                              float* __restrict__ out, int last) {
    int wid = (blockIdx.x << 2) + (threadIdx.x >> 6);
    int lane = threadIdx.x & 63;
    if (wid >= N_NODES) return;
    const int g = lane >> 3;
    const int sl = lane & 7;
    const int e0 = offs[wid], e1 = offs[wid + 1];
    float acc[8] = {};
    int e = e0;
    for (; e + 32 <= e1; e += 32) {
        int c0 = ccol[e + g];
        int c1 = ccol[e + 8 + g];
        int c2 = ccol[e + 16 + g];
        int c3 = ccol[e + 24 + g];
        half8 v0 = *(const half8*)(src + (long long)c0 * CLS + sl * 8);
        half8 v1 = *(const half8*)(src + (long long)c1 * CLS + sl * 8);
        half8 v2 = *(const half8*)(src + (long long)c2 * CLS + sl * 8);
        half8 v3 = *(const half8*)(src + (long long)c3 * CLS + sl * 8);
#pragma unroll
        for (int j = 0; j < 8; j++)
            acc[j] += ((float)v0[j] + (float)v1[j]) + ((float)v2[j] + (float)v3[j]);
    }
    if (e + 16 <= e1) {
        int c0 = ccol[e + g];
        int c1 = ccol[e + 8 + g];
        half8 v0 = *(const half8*)(src + (long long)c0 * CLS + sl * 8);
        half8 v1 = *(const half8*)(src + (long long)c1 * CLS + sl * 8);
#pragma unroll
        for (int j = 0; j < 8; j++) acc[j] += (float)v0[j] + (float)v1[j];
        e += 16;
    }
    if (e + 8 <= e1) {
        int c0 = ccol[e + g];
        half8 v0 = *(const half8*)(src + (long long)c0 * CLS + sl * 8);
#pragma unroll
        for (int j = 0; j < 8; j++) acc[j] += (float)v0[j];
        e += 8;
    }
    if (e < e1) {
        int idx = e + g;
        if (idx < e1) {
            int c = ccol[idx];
            half8 v = *(const half8*)(src + (long long)c * CLS + sl * 8);
#pragma unroll
            for (int j = 0; j < 8; j++) acc[j] += (float)v[j];
        }
    }
    // reduce across the 8 edge subgroups (lanes with same sl)
#pragma unroll
    for (int j = 0; j < 8; j++) {
        acc[j] += __shfl_xor(acc[j], 8);
        acc[j] += __shfl_xor(acc[j], 16);
        acc[j] += __shfl_xor(acc[j], 32);
    }

    float dr = dinv[wid];
    half8 hh = *(const half8*)(h + (long long)wid * CLS + sl * 8);
    float o[8];
#pragma unroll
    for (int j = 0; j < 8; j++) o[j] = 0.9f * dr * acc[j] + 0.1f * (float)hh[j];

    if (!last) {
        if (g == 0) {
            half8 ov;
#pragma unroll
            for (int j = 0; j < 8; j++) ov[j] = (_Float16)(dr * o[j]);
            *(half8*)(dst + (long long)wid * CLS + sl * 8) = ov;
        }
    } else {
        float m = o[0];
#pragma unroll
        for (int j = 1; j < 8; j++) m = fmaxf(m, o[j]);
        m = fmaxf(m, __shfl_xor(m, 1));
        m = fmaxf(m, __shfl_xor(m, 2));
        m = fmaxf(m, __shfl_xor(m, 4));
        float s = 0.f;
#pragma unroll
        for (int j = 0; j < 8; j++) s += expf(o[j] - m);
        s += __shfl_xor(s, 1);
        s += __shfl_xor(s, 2);
        s += __shfl_xor(s, 4);
        float ls = logf(s);
        if (g == 0) {
            float4 ov0 = make_float4(o[0] - m - ls, o[1] - m - ls, o[2] - m - ls, o[3] - m - ls);
            float4 ov1 = make_float4(o[4] - m - ls, o[5] - m - ls, o[6] - m - ls, o[7] - m - ls);
            *(float4*)(out + (long long)wid * CLS + sl * 8) = ov0;
            *(float4*)(out + (long long)wid * CLS + sl * 8 + 4) = ov1;
        }
    }
}

extern "C" void kernel_launch(void* const* d_in, const int* in_sizes, int n_in,
                              void* d_out, int out_size, void* d_ws, size_t ws_size,
                              hipStream_t stream) {
    const float* x  = (const float*)d_in[0];
    const void*  ei = d_in[1];
    const float* W1 = (const float*)d_in[2];
    const float* b1 = (const float*)d_in[3];
    const float* W2 = (const float*)d_in[4];
    const float* b2 = (const float*)d_in[5];
    float* out = (float*)d_out;

    char* p = (char*)d_ws;
    size_t off = 0;
    auto alloc = [&](size_t bytes) {
        char* q = p + off;
        off = (off + bytes + 255) & ~(size_t)255;
        return q;
    };
    int*      flag   = (int*)alloc(16);
    float*    dinv   = (float*)alloc((size_t)N_NODES * 4);
    int*      offs   = (int*)alloc((size_t)(N_NODES + 1) * 4);
    int*      bcntR  = (int*)alloc((NBUCK + 1) * 4);
    int*      bcntC  = (int*)alloc((NBUCK + 1) * 4);
    int*      bbaseR = (int*)alloc((NBUCK + 1) * 4);
    int*      bbaseC = (int*)alloc((NBUCK + 1) * 4);
    int*      cbase  = (int*)alloc((NBUCK + 1) * 4);
    int*      histR  = (int*)alloc((size_t)NCHUNK * NBUCK * 4);
    int*      histC  = (int*)alloc((size_t)NCHUNK * NBUCK * 4);
    int*      baseR  = (int*)alloc((size_t)NCHUNK * NBUCK * 4);
    int*      baseC  = (int*)alloc((size_t)NCHUNK * NBUCK * 4);
    unsigned* pairs  = (unsigned*)alloc((size_t)N_EDGES * 4);
    int*      cvals  = (int*)alloc((size_t)N_EDGES * 4);
    int*      ccol   = (int*)alloc(((size_t)N_EDGES + N_NODES + 64) * 4);
    _Float16* h      = (_Float16*)alloc((size_t)N_NODES * CLS * 2);
    _Float16* s0     = (_Float16*)alloc((size_t)N_NODES * CLS * 2);
    _Float16* bufA   = (_Float16*)alloc((size_t)N_NODES * CLS * 2);
    _Float16* bufB   = (_Float16*)alloc((size_t)N_NODES * CLS * 2);
    _Float16* h1     = (_Float16*)alloc((size_t)N_NODES * HID * 2);
    _Float16* W1T    = (_Float16*)alloc((size_t)HID * FEAT * 2);
    _Float16* W2T    = (_Float16*)alloc((size_t)CLS * HID * 2);
    (void)ws_size;

    // graph build (3-phase radix: hist -> scans -> place; then per-bucket CSR)
    k_detect<<<1, 256, 0, stream>>>((const unsigned*)ei, flag, bcntR, bcntC);
    k_bhist<<<NCHUNK, 256, 0, stream>>>(ei, flag, bcntR, bcntC, histR, histC);
    k_bscan<<<1, 64, 0, stream>>>(bcntR, bcntC, bbaseR, bbaseC, cbase, offs);
    k_bscan2<<<2 * NBUCK, 256, 0, stream>>>(histR, bbaseR, baseR, histC, bbaseC, baseC);
    k_binA<<<NCHUNK, 256, 0, stream>>>(ei, flag, baseR, baseC, pairs, cvals);
    k_bins<<<2 * NBUCK, 1024, 0, stream>>>(cvals, bbaseC, dinv, pairs, bbaseR, cbase,
                                           offs, ccol);

    // dense layers (fp16 MFMA)
    k_cvtW<<<512, 256, 0, stream>>>(W1, W2, W1T, W2T);
    k_gemm1<<<(N_NODES + 127) / 128, 512, 0, stream>>>(x, W1T, b1, h1, N_NODES);
    k_gemm2<<<(N_NODES + 255) / 256, 512, 0, stream>>>(h1, W2T, b2, dinv, h, s0, N_NODES);

    // K propagation steps; final step fuses log_softmax
    const int pgrid = (N_NODES + 3) / 4;
    _Float16* ping[2] = {bufA, bufB};
    for (int it = 0; it < K_ITER; it++) {
        const _Float16* src = (it == 0) ? s0 : ping[(it - 1) & 1];
        _Float16* dst = ping[it & 1];
        k_prop<<<pgrid, 256, 0, stream>>>(ccol, offs, dinv, src, h, dst, out,
                                          it == K_ITER - 1);
    }
}